// Round 12
// baseline (189.522 us; speedup 1.0000x reference)
//
#include <hip/hip_runtime.h>
#include <math.h>

#define LN_EPS 1e-5f
#define SCALE_QK 0.17677669529663687f  // 1/sqrt(32)

using bf16x8 = __bf16 __attribute__((ext_vector_type(8)));
using f32x4 = float __attribute__((ext_vector_type(4)));

__device__ __forceinline__ ushort f2bf(float f) {
  unsigned u = __float_as_uint(f);
  u += 0x7fff + ((u >> 16) & 1);  // RNE
  return (ushort)(u >> 16);
}

__device__ __forceinline__ unsigned cvt_pk_bf16(float a, float b) {
  // packed {lo=bf16(a), hi=bf16(b)}, hardware RNE
  unsigned r;
  asm("v_cvt_pk_bf16_f32 %0, %1, %2" : "=v"(r) : "v"(a), "v"(b));
  return r;
}

__device__ __forceinline__ void gload_lds16(const ushort* g, ushort* l) {
  __builtin_amdgcn_global_load_lds((__attribute__((address_space(1))) void*)g,
                                   (__attribute__((address_space(3))) void*)l, 16, 0, 0);
}

// Rule-#18 LDS fence: asm s_waitcnt with "memory" clobber (IR-level ordering)
// + sched_barrier(0) (pins post-RA movement).
__device__ __forceinline__ void fence_lgkm0() {
  asm volatile("s_waitcnt lgkmcnt(0)" ::: "memory");
  __builtin_amdgcn_sched_barrier(0);
}

// ---------------------------------------------------------------------------
// Merged prep: blocks 0-2047 cast x -> bf16 (4 float4/thread);
// 2048-2111 q_w, 2112-2239 kv_w, 2240-2303 out_w casts;
// 2304-2559 conv_w transpose (oc,ic,4,4) -> wTb[oc][pos*256+ic] bf16.
// ---------------------------------------------------------------------------
__global__ __launch_bounds__(256) void prep_kernel(
    const float* __restrict__ x, ushort* __restrict__ xb,
    const float* __restrict__ qw, const float* __restrict__ kvw,
    const float* __restrict__ ow, const float* __restrict__ cw,
    ushort* __restrict__ qwb, ushort* __restrict__ kvwb,
    ushort* __restrict__ owb, ushort* __restrict__ wTb) {
  int blk = blockIdx.x, tid = threadIdx.x;
  if (blk < 2048) {
    int i = blk * 1024 + tid;
#pragma unroll
    for (int p = 0; p < 4; ++p) {
      float4 v = ((const float4*)x)[i + p * 256];
      ushort4 o = {f2bf(v.x), f2bf(v.y), f2bf(v.z), f2bf(v.w)};
      ((ushort4*)xb)[i + p * 256] = o;
    }
  } else if (blk < 2304) {
    int b2 = blk - 2048;
    const float* src;
    ushort* dst;
    int i;
    if (b2 < 64) { src = qw; dst = qwb; i = b2 * 256 + tid; }
    else if (b2 < 192) { src = kvw; dst = kvwb; i = (b2 - 64) * 256 + tid; }
    else { src = ow; dst = owb; i = (b2 - 192) * 256 + tid; }
    float4 v = ((const float4*)src)[i];
    ushort4 o = {f2bf(v.x), f2bf(v.y), f2bf(v.z), f2bf(v.w)};
    ((ushort4*)dst)[i] = o;
  } else {
    int oc = blk - 2304, ic = tid;
    const float* src = cw + (size_t)oc * 4096 + ic * 16;
#pragma unroll
    for (int pos = 0; pos < 16; ++pos)
      wTb[(size_t)oc * 4096 + pos * 256 + ic] = f2bf(src[pos]);
  }
}

// ---------------------------------------------------------------------------
// MERGED conv patch-GEMM (split-K=2, K-step 64 via twin 32-col tiles -- the
// proven r10 BK; r11 showed BK=128 regresses) + Q projection (B-in-register).
// Split-K 4->2: halves the fp32 partial round-trip (8->4 MB each way) and
// ln's reduce depth; conv drops to 128 blocks (Q's 512 blocks keep CUs full).
// Same-(m,bz) blocks across n differ by 32 in id -> same XCD L2.
// ---------------------------------------------------------------------------
__global__ __launch_bounds__(256, 2) void convq_kernel(
    const ushort* __restrict__ xb, const ushort* __restrict__ wTb,
    float* __restrict__ part, const ushort* __restrict__ qwb,
    const float* __restrict__ qbias, ushort* __restrict__ qbb) {
  __shared__ __attribute__((aligned(16))) ushort As[2][128 * 32];
  __shared__ __attribute__((aligned(16))) ushort Bs[2][64 * 32];
  int tid = threadIdx.x, lane = tid & 63, w = tid >> 6;
  int l15 = lane & 15, quad = lane >> 4;
  int id = blockIdx.x;
  if (id < 128) {
    // ---- conv patch-GEMM, tile 128x64, split-K=2, K-step 64 ----
    // id = n*32 + bz*16 + m : same (m,bz) across n differ by 32 (same XCD)
    int m0 = (id & 15) * 128;
    int bz = (id >> 4) & 1;
    int n0 = (id >> 5) * 64;
    int arow0 = w * 16 + (lane >> 2);
    int acol = (lane & 3) * 8;
    int kbase = bz * 2048;
    f32x4 acc[2][4];
#pragma unroll
    for (int i = 0; i < 2; ++i)
#pragma unroll
      for (int j = 0; j < 4; ++j) acc[i][j] = (f32x4){0.f, 0.f, 0.f, 0.f};

    for (int k0 = 0; k0 < 2048; k0 += 64) {
      int kg = kbase + k0;
      __syncthreads();
#pragma unroll
      for (int s = 0; s < 2; ++s) {
#pragma unroll
        for (int t = 0; t < 2; ++t) {
          int row = arow0 + t * 64;
          int m = m0 + row;
          int b = m >> 8, mm = m & 255;
          int oh = mm >> 4, ow_ = mm & 15;
          int k = kg + s * 32 + acol;
          int pos = k >> 8, ic = k & 255;
          int n = ((oh << 2) + (pos >> 2)) * 64 + (ow_ << 2) + (pos & 3);
          gload_lds16(xb + ((size_t)(b * 4096 + n) * 256 + ic),
                      &As[s][t * 2048 + w * 512]);
        }
        gload_lds16(wTb + ((size_t)(n0 + w * 16 + (lane >> 2)) * 4096 + kg +
                           s * 32 + acol),
                    &Bs[s][w * 512]);
      }
      __syncthreads();
      int qk = quad * 8;
#pragma unroll
      for (int s = 0; s < 2; ++s) {
        bf16x8 a0 = *(const bf16x8*)&As[s][(w * 32 + l15) * 32 + qk];
        bf16x8 a1 = *(const bf16x8*)&As[s][(w * 32 + 16 + l15) * 32 + qk];
#pragma unroll
        for (int j = 0; j < 4; ++j) {
          bf16x8 bj = *(const bf16x8*)&Bs[s][(j * 16 + l15) * 32 + qk];
          acc[0][j] = __builtin_amdgcn_mfma_f32_16x16x32_bf16(a0, bj, acc[0][j], 0, 0, 0);
          acc[1][j] = __builtin_amdgcn_mfma_f32_16x16x32_bf16(a1, bj, acc[1][j], 0, 0, 0);
        }
      }
    }
    float* Cz = part + (size_t)bz * 524288;
#pragma unroll
    for (int i = 0; i < 2; ++i)
#pragma unroll
      for (int j = 0; j < 4; ++j) {
        int col = n0 + j * 16 + l15;
#pragma unroll
        for (int r = 0; r < 4; ++r) {
          int row = m0 + w * 32 + i * 16 + quad * 4 + r;
          Cz[(size_t)row * 256 + col] = acc[i][j][r];
        }
      }
  } else {
    // ---- Q projection (B-in-register, K=256), scale folded in ----
    // qid = n*128 + m : same m across n differ by 128 (== same XCD)
    const float Cc = SCALE_QK * 1.4426950408889634f;  // scale * log2(e)
    int qid = id - 128;
    int n0 = (qid >> 7) * 64;
    int m0 = (qid & 127) * 256 + w * 64;
    bf16x8 bfr[4][8];
    const ushort* bbase = qwb + (size_t)(n0 + l15) * 256 + quad * 8;
#pragma unroll
    for (int j = 0; j < 4; ++j)
#pragma unroll
      for (int kc = 0; kc < 8; ++kc)
        bfr[j][kc] = *(const bf16x8*)(bbase + (size_t)j * 16 * 256 + kc * 32);
    float bv[4];
#pragma unroll
    for (int j = 0; j < 4; ++j) bv[j] = qbias[n0 + j * 16 + l15];

#pragma unroll
    for (int t = 0; t < 4; ++t) {
      const ushort* arow = xb + (size_t)(m0 + t * 16 + l15) * 256 + quad * 8;
      bf16x8 af[8];
#pragma unroll
      for (int kc = 0; kc < 8; ++kc) af[kc] = *(const bf16x8*)(arow + kc * 32);
      f32x4 acc[4];
#pragma unroll
      for (int j = 0; j < 4; ++j) acc[j] = (f32x4){0.f, 0.f, 0.f, 0.f};
#pragma unroll
      for (int kc = 0; kc < 8; ++kc)
#pragma unroll
        for (int j = 0; j < 4; ++j)
          acc[j] = __builtin_amdgcn_mfma_f32_16x16x32_bf16(af[kc], bfr[j][kc], acc[j], 0, 0, 0);
#pragma unroll
      for (int j = 0; j < 4; ++j)
#pragma unroll
        for (int r = 0; r < 4; ++r) {
          int row = m0 + t * 16 + quad * 4 + r;
          int col = n0 + j * 16 + l15;
          qbb[(size_t)row * 256 + col] = f2bf((acc[j][r] + bv[j]) * Cc);
        }
    }
  }
}

// ---------------------------------------------------------------------------
// B-in-register MFMA GEMM for K=256, N=256 (final out projection, fp32 out).
// Grid (128 m, 4 n): same-A blocks differ by 128 in linear id -> same XCD.
// ---------------------------------------------------------------------------
__global__ __launch_bounds__(256, 2) void breg_gemm_f32(const ushort* __restrict__ A,
                                                        const ushort* __restrict__ Bw,
                                                        const float* __restrict__ bias,
                                                        float* __restrict__ Cf) {
  int tid = threadIdx.x, lane = tid & 63, w = tid >> 6;
  int l15 = lane & 15, quad = lane >> 4;
  int n0 = blockIdx.y * 64;
  int m0 = blockIdx.x * 256 + w * 64;
  bf16x8 bfr[4][8];
  const ushort* bbase = Bw + (size_t)(n0 + l15) * 256 + quad * 8;
#pragma unroll
  for (int j = 0; j < 4; ++j)
#pragma unroll
    for (int kc = 0; kc < 8; ++kc)
      bfr[j][kc] = *(const bf16x8*)(bbase + (size_t)j * 16 * 256 + kc * 32);
  float bv[4];
#pragma unroll
  for (int j = 0; j < 4; ++j) bv[j] = bias[n0 + j * 16 + l15];

#pragma unroll
  for (int t = 0; t < 4; ++t) {
    const ushort* arow = A + (size_t)(m0 + t * 16 + l15) * 256 + quad * 8;
    bf16x8 af[8];
#pragma unroll
    for (int kc = 0; kc < 8; ++kc) af[kc] = *(const bf16x8*)(arow + kc * 32);
    f32x4 acc[4];
#pragma unroll
    for (int j = 0; j < 4; ++j) acc[j] = (f32x4){0.f, 0.f, 0.f, 0.f};
#pragma unroll
    for (int kc = 0; kc < 8; ++kc)
#pragma unroll
      for (int j = 0; j < 4; ++j)
        acc[j] = __builtin_amdgcn_mfma_f32_16x16x32_bf16(af[kc], bfr[j][kc], acc[j], 0, 0, 0);
#pragma unroll
    for (int j = 0; j < 4; ++j)
#pragma unroll
      for (int r = 0; r < 4; ++r) {
        int row = m0 + t * 16 + quad * 4 + r;
        int col = n0 + j * 16 + l15;
        Cf[(size_t)row * 256 + col] = acc[j][r] + bv[j];
      }
  }
}

// ---------------------------------------------------------------------------
// Fused split-K(2) reduce + conv bias + LayerNorm -> bf16.
// Wave-per-token (4 tokens/block, grid 512). (Structure verified r7-r11;
// reduce depth now 2 slices.)
// ---------------------------------------------------------------------------
__global__ __launch_bounds__(256) void ln_fused(const float* __restrict__ part,
                                                const float* __restrict__ cb,
                                                const float* __restrict__ g,
                                                const float* __restrict__ bt,
                                                ushort* __restrict__ x1b) {
  int tid = threadIdx.x;
  int tok = blockIdx.x * 4 + (tid >> 6);
  int lane = tid & 63;
  size_t base = (size_t)tok * 256 + lane * 4;
  float4 c = *(const float4*)(cb + lane * 4);
  float4 v = c;
#pragma unroll
  for (int z = 0; z < 2; ++z) {
    float4 p = *(const float4*)(part + base + (size_t)z * 524288);
    v.x += p.x; v.y += p.y; v.z += p.z; v.w += p.w;
  }
  float s1 = v.x + v.y + v.z + v.w;
  float s2 = v.x * v.x + v.y * v.y + v.z * v.z + v.w * v.w;
#pragma unroll
  for (int o = 1; o < 64; o <<= 1) {
    s1 += __shfl_xor(s1, o, 64);
    s2 += __shfl_xor(s2, o, 64);
  }
  float mu = s1 * (1.f / 256.f);
  float var = s2 * (1.f / 256.f) - mu * mu;
  float rstd = rsqrtf(var + LN_EPS);
  float4 gg = *(const float4*)(g + lane * 4);
  float4 bb = *(const float4*)(bt + lane * 4);
  ushort4 o4 = {f2bf((v.x - mu) * rstd * gg.x + bb.x),
                f2bf((v.y - mu) * rstd * gg.y + bb.y),
                f2bf((v.z - mu) * rstd * gg.z + bb.z),
                f2bf((v.w - mu) * rstd * gg.w + bb.w)};
  *(ushort4*)(x1b + base) = o4;
}

// ---------------------------------------------------------------------------
// KV projection GEMM, K-step 64 via twin 32-col tiles. (r10 passing verbatim;
// r11's BK=128 variant regressed and is reverted.)
// Grid (16 m, 8 n): same-A blocks differ by 16 in linear id -> same XCD.
// ---------------------------------------------------------------------------
__global__ __launch_bounds__(256) void kv_gemm(const ushort* __restrict__ A,
                                               const ushort* __restrict__ Bw,
                                               const float* __restrict__ bias,
                                               ushort* __restrict__ aux,
                                               ushort* __restrict__ aux2) {
  __shared__ __attribute__((aligned(16))) ushort As[2][128 * 32];
  __shared__ __attribute__((aligned(16))) ushort Bs[2][64 * 32];
  int tid = threadIdx.x;
  int lane = tid & 63, w = tid >> 6;
  int m0 = blockIdx.x * 128, n0 = blockIdx.y * 64;
  int arow0 = w * 16 + (lane >> 2);
  int acol = (lane & 3) * 8;
  f32x4 acc[2][4];
#pragma unroll
  for (int i = 0; i < 2; ++i)
#pragma unroll
    for (int j = 0; j < 4; ++j) acc[i][j] = (f32x4){0.f, 0.f, 0.f, 0.f};

  for (int k0 = 0; k0 < 256; k0 += 64) {
    __syncthreads();
#pragma unroll
    for (int s = 0; s < 2; ++s) {
#pragma unroll
      for (int t = 0; t < 2; ++t) {
        int row = arow0 + t * 64;
        gload_lds16(A + ((size_t)(m0 + row) * 256 + k0 + s * 32 + acol),
                    &As[s][t * 2048 + w * 512]);
      }
      gload_lds16(Bw + ((size_t)(n0 + w * 16 + (lane >> 2)) * 256 + k0 + s * 32 + acol),
                  &Bs[s][w * 512]);
    }
    __syncthreads();
    int qk = (lane >> 4) * 8, l15 = lane & 15;
#pragma unroll
    for (int s = 0; s < 2; ++s) {
      bf16x8 a0 = *(const bf16x8*)&As[s][(w * 32 + l15) * 32 + qk];
      bf16x8 a1 = *(const bf16x8*)&As[s][(w * 32 + 16 + l15) * 32 + qk];
#pragma unroll
      for (int j = 0; j < 4; ++j) {
        bf16x8 bj = *(const bf16x8*)&Bs[s][(j * 16 + l15) * 32 + qk];
        acc[0][j] = __builtin_amdgcn_mfma_f32_16x16x32_bf16(a0, bj, acc[0][j], 0, 0, 0);
        acc[1][j] = __builtin_amdgcn_mfma_f32_16x16x32_bf16(a1, bj, acc[1][j], 0, 0, 0);
      }
    }
  }
  int l15 = lane & 15, q = lane >> 4;
#pragma unroll
  for (int i = 0; i < 2; ++i) {
    int rowb = m0 + w * 32 + i * 16 + q * 4;
    int b = rowb >> 8, mloc = rowb & 255;
#pragma unroll
    for (int j = 0; j < 4; ++j) {
      int col = n0 + j * 16 + l15;
      float bv = bias[col];
      if (col < 256) {  // K half
#pragma unroll
        for (int r = 0; r < 4; ++r)
          aux[(size_t)(b * 256 + mloc + r) * 256 + col] = f2bf(acc[i][j][r] + bv);
      } else {  // V half -> vT[((b*8+h)*32+d)][m]
        int c2 = col - 256, h = c2 >> 5, d = c2 & 31;
        unsigned lo = (unsigned)f2bf(acc[i][j][0] + bv) |
                      ((unsigned)f2bf(acc[i][j][1] + bv) << 16);
        unsigned hi = (unsigned)f2bf(acc[i][j][2] + bv) |
                      ((unsigned)f2bf(acc[i][j][3] + bv) << 16);
        *(uint2*)(aux2 + ((size_t)((b * 8 + h) * 32 + d) * 256 + mloc)) =
            make_uint2(lo, hi);
      }
    }
  }
}

// ---------------------------------------------------------------------------
// MFMA flash attention v8 (r10 passing version, verbatim): 2-deep software
// pipeline over t; double per-wave P buffer; compile-time buffer selection;
// rule-#18 fence between pack(t) writes and PV(t) reads.
// ---------------------------------------------------------------------------
__global__ __launch_bounds__(256) void attn_mfma(const ushort* __restrict__ qbb,
                                                 const ushort* __restrict__ kb,
                                                 const ushort* __restrict__ vT,
                                                 ushort* __restrict__ aob) {
  // 67584 B: first 32 KB doubles as K/V staging, then 4 waves x 2 P buffers.
  __shared__ __attribute__((aligned(16))) ushort sh[2 * 4 * 16 * 264];
  int bid = blockIdx.x;  // 512: b = bid&7 (XCD-local), h = (bid>>3)&7, cp = bid>>6
  int b = bid & 7, h = (bid >> 3) & 7, cp = bid >> 6;
  int tid = threadIdx.x, lane = tid & 63, w = tid >> 6;
  int l15 = lane & 15, quad = lane >> 4;

  // ---- stage K-head -> sh[0..8192) as [m][32]; V-head -> sh[8192..16384) as [d][256]
  {
    const ushort* srcK = kb + (size_t)(b * 256 + w * 64 + (lane >> 2)) * 256 +
                         h * 32 + (lane & 3) * 8;
#pragma unroll
    for (int i = 0; i < 4; ++i)
      gload_lds16(srcK + (size_t)i * 16 * 256, &sh[(w * 64 + i * 16) * 32]);
    const ushort* srcV = vT + (size_t)((b * 8 + h) * 32 + w * 8 + (lane >> 5)) * 256 +
                         (lane & 31) * 8;
#pragma unroll
    for (int i = 0; i < 4; ++i)
      gload_lds16(srcV + (size_t)i * 2 * 256, &sh[8192 + (w * 8 + i * 2) * 256]);
  }
  __syncthreads();  // staging visible (drains vmcnt)
  // ---- extract register fragments (one-time)
  bf16x8 kf[16];
#pragma unroll
  for (int mt = 0; mt < 16; ++mt)
    kf[mt] = *(const bf16x8*)&sh[(mt * 16 + l15) * 32 + quad * 8];
  bf16x8 vf[2][8];
#pragma unroll
  for (int j = 0; j < 2; ++j)
#pragma unroll
    for (int kc = 0; kc < 8; ++kc)
      vf[j][kc] = *(const bf16x8*)&sh[8192 + (j * 16 + l15) * 256 + kc * 32 + quad * 8];
  __syncthreads();  // all frags extracted; sh now reusable as P buffers
  ushort* Pw0 = &sh[w * 2 * 4224];  // wave's buffer 0 (16 x 264)
  ushort* Pw1 = Pw0 + 4224;         // wave's buffer 1

  int q0base = b * 4096 + cp * 512 + w * 64;

  // QK^T + exp + pack for q-tile t into buffer Pw; returns fully-reduced lsum.
  auto QKEP = [&](bf16x8 qf, ushort* Pw) -> float {
    float lsum = 0.f;
#pragma unroll
    for (int mt = 0; mt < 16; ++mt) {
      f32x4 st = __builtin_amdgcn_mfma_f32_16x16x32_bf16(
          kf[mt], qf, (f32x4){0.f, 0.f, 0.f, 0.f}, 0, 0, 0);
      float e0 = __builtin_amdgcn_exp2f(st[0]);
      float e1 = __builtin_amdgcn_exp2f(st[1]);
      float e2 = __builtin_amdgcn_exp2f(st[2]);
      float e3 = __builtin_amdgcn_exp2f(st[3]);
      lsum += e0 + e1 + e2 + e3;  // pre-round sum; RNE of stored P is mean-zero
      unsigned lo = cvt_pk_bf16(e0, e1);
      unsigned hi = cvt_pk_bf16(e2, e3);
      *(uint2*)(Pw + l15 * 264 + mt * 16 + quad * 4) = make_uint2(lo, hi);
    }
    lsum += __shfl_xor(lsum, 16, 64);
    lsum += __shfl_xor(lsum, 32, 64);
    return lsum;
  };
  auto qptr = [&](int t) {
    int q0 = q0base + ((t & 4) << 6) + (t & 3) * 16;
    return (const bf16x8*)(qbb + (size_t)(q0 + l15) * 256 + h * 32 + quad * 8);
  };

  // prologue: fill buffer 0 for t=0
  float lsum_cur = QKEP(*qptr(0), Pw0);

#pragma unroll
  for (int t = 0; t < 8; ++t) {
    ushort* Prd = (t & 1) ? Pw1 : Pw0;  // compile-time after unroll
    ushort* Pwr = (t & 1) ? Pw0 : Pw1;
    bf16x8 qf_next;
    if (t < 7) qf_next = *qptr(t + 1);  // issue early; hides under fence+PV
    fence_lgkm0();  // pack(t) writes complete & ordered before PV reads
    f32x4 oacc[2] = {{0.f, 0.f, 0.f, 0.f}, {0.f, 0.f, 0.f, 0.f}};
#pragma unroll
    for (int kc = 0; kc < 8; ++kc) {
      bf16x8 pf = *(const bf16x8*)(Prd + l15 * 264 + kc * 32 + quad * 8);
      oacc[0] = __builtin_amdgcn_mfma_f32_16x16x32_bf16(pf, vf[0][kc], oacc[0], 0, 0, 0);
      oacc[1] = __builtin_amdgcn_mfma_f32_16x16x32_bf16(pf, vf[1][kc], oacc[1], 0, 0, 0);
    }
    // QK+exp+pack for t+1 (independent of PV above -> scheduler interleaves)
    float lsum_next = 0.f;
    if (t < 7) lsum_next = QKEP(qf_next, Pwr);
    // epilogue for t
    float linv[4];
#pragma unroll
    for (int r = 0; r < 4; ++r)
      linv[r] = __builtin_amdgcn_rcpf(__shfl(lsum_cur, quad * 4 + r, 64));
    int q0 = q0base + ((t & 4) << 6) + (t & 3) * 16;
    ushort* ob = aob + (size_t)q0 * 256 + h * 32;
#pragma unroll
    for (int j = 0; j < 2; ++j)
#pragma unroll
      for (int r = 0; r < 4; ++r) {
        unsigned uo = __float_as_uint(oacc[j][r] * linv[r]) + 0x8000u;
        ob[(size_t)(quad * 4 + r) * 256 + j * 16 + l15] = (ushort)(uo >> 16);
      }
    lsum_cur = lsum_next;
  }
}

// ---------------------------------------------------------------------------
extern "C" void kernel_launch(void* const* d_in, const int* in_sizes, int n_in,
                              void* d_out, int out_size, void* d_ws, size_t ws_size,
                              hipStream_t stream) {
  const float* x = (const float*)d_in[0];
  const float* conv_w = (const float*)d_in[1];
  const float* conv_b = (const float*)d_in[2];
  const float* ln_g = (const float*)d_in[3];
  const float* ln_b = (const float*)d_in[4];
  const float* kv_w = (const float*)d_in[5];
  const float* kv_b = (const float*)d_in[6];
  const float* q_w = (const float*)d_in[7];
  const float* q_b = (const float*)d_in[8];
  const float* out_w = (const float*)d_in[9];
  const float* out_b = (const float*)d_in[10];

  // workspace (~22.4 MB)
  ushort* xb = (ushort*)d_ws;                  // 8,388,608 bf16; aliased as aob later
  ushort* wTb = xb + 8388608;                  // 1,048,576 bf16
  ushort* qwb = wTb + 1048576;                 // 65,536
  ushort* kvwb = qwb + 65536;                  // 131,072
  ushort* owb = kvwb + 131072;                 // 65,536
  ushort* x1b = owb + 65536;                   // 524,288 bf16
  ushort* kb = x1b + 524288;                   // 524,288 bf16: K [b*256+m][256]
  ushort* vT = kb + 524288;                    // 524,288 bf16: V^T [((b*8+h)*32+d)][m]
  ushort* aob = xb;                            // attention out, reuses xb
  // d_out (33.55 MB fp32) doubles as scratch before the final projection:
  float* part = (float*)d_out;                 // 2 x 524,288 f32 conv partials
  ushort* qbb = (ushort*)((float*)d_out + 4194304);  // 8,388,608 bf16 Q

  prep_kernel<<<2560, 256, 0, stream>>>(x, xb, q_w, kv_w, out_w, conv_w,
                                        qwb, kvwb, owb, wTb);
  // merged: conv patch-GEMM split-K=2 (blocks 0-127) + Q projection (128-639)
  convq_kernel<<<640, 256, 0, stream>>>(xb, wTb, part, qwb, q_b, qbb);
  // fused reduce(2) + bias + LayerNorm -> x1b bf16 (wave-per-token)
  ln_fused<<<512, 256, 0, stream>>>(part, conv_b, ln_g, ln_b, x1b);
  // KV projection -> K bf16 (kb) + V^T bf16 (vT)
  kv_gemm<<<dim3(16, 8), 256, 0, stream>>>(x1b, kvwb, kv_b, kb, vT);
  // MFMA flash attention -> aob bf16 (aliases xb; xb dead after convq)
  attn_mfma<<<512, 256, 0, stream>>>(qbb, kb, vT, aob);
  // output projection -> d_out fp32 (overwrites the scratch halves)
  breg_gemm_f32<<<dim3(128, 4), 256, 0, stream>>>(aob, owb, out_b, (float*)d_out);
}

// Round 13
// 181.210 us; speedup vs baseline: 1.0459x; 1.0459x over previous
//
#include <hip/hip_runtime.h>
#include <math.h>

#define LN_EPS 1e-5f
#define SCALE_QK 0.17677669529663687f  // 1/sqrt(32)

using bf16x8 = __bf16 __attribute__((ext_vector_type(8)));
using f32x4 = float __attribute__((ext_vector_type(4)));

__device__ __forceinline__ ushort f2bf(float f) {
  unsigned u = __float_as_uint(f);
  u += 0x7fff + ((u >> 16) & 1);  // RNE
  return (ushort)(u >> 16);
}

__device__ __forceinline__ unsigned cvt_pk_bf16(float a, float b) {
  // packed {lo=bf16(a), hi=bf16(b)}, hardware RNE
  unsigned r;
  asm("v_cvt_pk_bf16_f32 %0, %1, %2" : "=v"(r) : "v"(a), "v"(b));
  return r;
}

__device__ __forceinline__ void gload_lds16(const ushort* g, ushort* l) {
  __builtin_amdgcn_global_load_lds((__attribute__((address_space(1))) void*)g,
                                   (__attribute__((address_space(3))) void*)l, 16, 0, 0);
}

// Rule-#18 LDS fence: asm s_waitcnt with "memory" clobber (IR-level ordering)
// + sched_barrier(0) (pins post-RA movement).
__device__ __forceinline__ void fence_lgkm0() {
  asm volatile("s_waitcnt lgkmcnt(0)" ::: "memory");
  __builtin_amdgcn_sched_barrier(0);
}

// ---------------------------------------------------------------------------
// Merged prep: blocks 0-2047 cast x -> bf16 (4 float4/thread);
// 2048-2111 q_w, 2112-2239 kv_w, 2240-2303 out_w casts;
// 2304-2559 conv_w transpose (oc,ic,4,4) -> wTb[oc][pos*256+ic] bf16.
// ---------------------------------------------------------------------------
__global__ __launch_bounds__(256) void prep_kernel(
    const float* __restrict__ x, ushort* __restrict__ xb,
    const float* __restrict__ qw, const float* __restrict__ kvw,
    const float* __restrict__ ow, const float* __restrict__ cw,
    ushort* __restrict__ qwb, ushort* __restrict__ kvwb,
    ushort* __restrict__ owb, ushort* __restrict__ wTb) {
  int blk = blockIdx.x, tid = threadIdx.x;
  if (blk < 2048) {
    int i = blk * 1024 + tid;
#pragma unroll
    for (int p = 0; p < 4; ++p) {
      float4 v = ((const float4*)x)[i + p * 256];
      ushort4 o = {f2bf(v.x), f2bf(v.y), f2bf(v.z), f2bf(v.w)};
      ((ushort4*)xb)[i + p * 256] = o;
    }
  } else if (blk < 2304) {
    int b2 = blk - 2048;
    const float* src;
    ushort* dst;
    int i;
    if (b2 < 64) { src = qw; dst = qwb; i = b2 * 256 + tid; }
    else if (b2 < 192) { src = kvw; dst = kvwb; i = (b2 - 64) * 256 + tid; }
    else { src = ow; dst = owb; i = (b2 - 192) * 256 + tid; }
    float4 v = ((const float4*)src)[i];
    ushort4 o = {f2bf(v.x), f2bf(v.y), f2bf(v.z), f2bf(v.w)};
    ((ushort4*)dst)[i] = o;
  } else {
    int oc = blk - 2304, ic = tid;
    const float* src = cw + (size_t)oc * 4096 + ic * 16;
#pragma unroll
    for (int pos = 0; pos < 16; ++pos)
      wTb[(size_t)oc * 4096 + pos * 256 + ic] = f2bf(src[pos]);
  }
}

// ---------------------------------------------------------------------------
// MERGED conv patch-GEMM (split-K=4, K-step 64 via twin 32-col tiles)
// + Q projection (B-in-register). BEST-KNOWN config (r10, 181.5us):
// r11 (BK=128) and r12 (split-K=2) both regressed -- "fewer, longer"
// blocks/steps lose to "more, shorter" once the machine is occupancy-fed.
// XCD-aware id decode keeps same-A-panel blocks on the same XCD L2.
// ---------------------------------------------------------------------------
__global__ __launch_bounds__(256, 2) void convq_kernel(
    const ushort* __restrict__ xb, const ushort* __restrict__ wTb,
    float* __restrict__ part, const ushort* __restrict__ qwb,
    const float* __restrict__ qbias, ushort* __restrict__ qbb) {
  __shared__ __attribute__((aligned(16))) ushort As[2][128 * 32];
  __shared__ __attribute__((aligned(16))) ushort Bs[2][64 * 32];
  int tid = threadIdx.x, lane = tid & 63, w = tid >> 6;
  int l15 = lane & 15, quad = lane >> 4;
  int id = blockIdx.x;
  if (id < 256) {
    int m0 = (id & 15) * 128;
    int bz = (id >> 4) & 3;
    int n0 = (id >> 6) * 64;
    int arow0 = w * 16 + (lane >> 2);
    int acol = (lane & 3) * 8;
    f32x4 acc[2][4];
#pragma unroll
    for (int i = 0; i < 2; ++i)
#pragma unroll
      for (int j = 0; j < 4; ++j) acc[i][j] = (f32x4){0.f, 0.f, 0.f, 0.f};

    for (int k0 = 0; k0 < 1024; k0 += 64) {
      int kg = bz * 1024 + k0;
      __syncthreads();
#pragma unroll
      for (int s = 0; s < 2; ++s) {
#pragma unroll
        for (int t = 0; t < 2; ++t) {
          int row = arow0 + t * 64;
          int m = m0 + row;
          int b = m >> 8, mm = m & 255;
          int oh = mm >> 4, ow_ = mm & 15;
          int k = kg + s * 32 + acol;
          int pos = k >> 8, ic = k & 255;
          int n = ((oh << 2) + (pos >> 2)) * 64 + (ow_ << 2) + (pos & 3);
          gload_lds16(xb + ((size_t)(b * 4096 + n) * 256 + ic),
                      &As[s][t * 2048 + w * 512]);
        }
        gload_lds16(wTb + ((size_t)(n0 + w * 16 + (lane >> 2)) * 4096 + kg +
                           s * 32 + acol),
                    &Bs[s][w * 512]);
      }
      __syncthreads();
      int qk = quad * 8;
#pragma unroll
      for (int s = 0; s < 2; ++s) {
        bf16x8 a0 = *(const bf16x8*)&As[s][(w * 32 + l15) * 32 + qk];
        bf16x8 a1 = *(const bf16x8*)&As[s][(w * 32 + 16 + l15) * 32 + qk];
#pragma unroll
        for (int j = 0; j < 4; ++j) {
          bf16x8 bj = *(const bf16x8*)&Bs[s][(j * 16 + l15) * 32 + qk];
          acc[0][j] = __builtin_amdgcn_mfma_f32_16x16x32_bf16(a0, bj, acc[0][j], 0, 0, 0);
          acc[1][j] = __builtin_amdgcn_mfma_f32_16x16x32_bf16(a1, bj, acc[1][j], 0, 0, 0);
        }
      }
    }
    float* Cz = part + (size_t)bz * 524288;
#pragma unroll
    for (int i = 0; i < 2; ++i)
#pragma unroll
      for (int j = 0; j < 4; ++j) {
        int col = n0 + j * 16 + l15;
#pragma unroll
        for (int r = 0; r < 4; ++r) {
          int row = m0 + w * 32 + i * 16 + quad * 4 + r;
          Cz[(size_t)row * 256 + col] = acc[i][j][r];
        }
      }
  } else {
    const float Cc = SCALE_QK * 1.4426950408889634f;  // scale * log2(e)
    int qid = id - 256;
    int n0 = (qid >> 7) * 64;
    int m0 = (qid & 127) * 256 + w * 64;
    bf16x8 bfr[4][8];
    const ushort* bbase = qwb + (size_t)(n0 + l15) * 256 + quad * 8;
#pragma unroll
    for (int j = 0; j < 4; ++j)
#pragma unroll
      for (int kc = 0; kc < 8; ++kc)
        bfr[j][kc] = *(const bf16x8*)(bbase + (size_t)j * 16 * 256 + kc * 32);
    float bv[4];
#pragma unroll
    for (int j = 0; j < 4; ++j) bv[j] = qbias[n0 + j * 16 + l15];

#pragma unroll
    for (int t = 0; t < 4; ++t) {
      const ushort* arow = xb + (size_t)(m0 + t * 16 + l15) * 256 + quad * 8;
      bf16x8 af[8];
#pragma unroll
      for (int kc = 0; kc < 8; ++kc) af[kc] = *(const bf16x8*)(arow + kc * 32);
      f32x4 acc[4];
#pragma unroll
      for (int j = 0; j < 4; ++j) acc[j] = (f32x4){0.f, 0.f, 0.f, 0.f};
#pragma unroll
      for (int kc = 0; kc < 8; ++kc)
#pragma unroll
        for (int j = 0; j < 4; ++j)
          acc[j] = __builtin_amdgcn_mfma_f32_16x16x32_bf16(af[kc], bfr[j][kc], acc[j], 0, 0, 0);
#pragma unroll
      for (int j = 0; j < 4; ++j)
#pragma unroll
        for (int r = 0; r < 4; ++r) {
          int row = m0 + t * 16 + quad * 4 + r;
          int col = n0 + j * 16 + l15;
          qbb[(size_t)row * 256 + col] = f2bf((acc[j][r] + bv[j]) * Cc);
        }
    }
  }
}

// ---------------------------------------------------------------------------
// B-in-register MFMA GEMM for K=256, N=256 (final out projection, fp32 out).
// Grid (128 m, 4 n): same-A blocks differ by 128 in linear id -> same XCD.
// ---------------------------------------------------------------------------
__global__ __launch_bounds__(256, 2) void breg_gemm_f32(const ushort* __restrict__ A,
                                                        const ushort* __restrict__ Bw,
                                                        const float* __restrict__ bias,
                                                        float* __restrict__ Cf) {
  int tid = threadIdx.x, lane = tid & 63, w = tid >> 6;
  int l15 = lane & 15, quad = lane >> 4;
  int n0 = blockIdx.y * 64;
  int m0 = blockIdx.x * 256 + w * 64;
  bf16x8 bfr[4][8];
  const ushort* bbase = Bw + (size_t)(n0 + l15) * 256 + quad * 8;
#pragma unroll
  for (int j = 0; j < 4; ++j)
#pragma unroll
    for (int kc = 0; kc < 8; ++kc)
      bfr[j][kc] = *(const bf16x8*)(bbase + (size_t)j * 16 * 256 + kc * 32);
  float bv[4];
#pragma unroll
  for (int j = 0; j < 4; ++j) bv[j] = bias[n0 + j * 16 + l15];

#pragma unroll
  for (int t = 0; t < 4; ++t) {
    const ushort* arow = A + (size_t)(m0 + t * 16 + l15) * 256 + quad * 8;
    bf16x8 af[8];
#pragma unroll
    for (int kc = 0; kc < 8; ++kc) af[kc] = *(const bf16x8*)(arow + kc * 32);
    f32x4 acc[4];
#pragma unroll
    for (int j = 0; j < 4; ++j) acc[j] = (f32x4){0.f, 0.f, 0.f, 0.f};
#pragma unroll
    for (int kc = 0; kc < 8; ++kc)
#pragma unroll
      for (int j = 0; j < 4; ++j)
        acc[j] = __builtin_amdgcn_mfma_f32_16x16x32_bf16(af[kc], bfr[j][kc], acc[j], 0, 0, 0);
#pragma unroll
    for (int j = 0; j < 4; ++j)
#pragma unroll
      for (int r = 0; r < 4; ++r) {
        int row = m0 + t * 16 + quad * 4 + r;
        int col = n0 + j * 16 + l15;
        Cf[(size_t)row * 256 + col] = acc[j][r] + bv[j];
      }
  }
}

// ---------------------------------------------------------------------------
// Fused split-K(4) reduce + conv bias + LayerNorm -> bf16.
// Wave-per-token (4 tokens/block, grid 512). (Verified passing, r7-r10.)
// ---------------------------------------------------------------------------
__global__ __launch_bounds__(256) void ln_fused(const float* __restrict__ part,
                                                const float* __restrict__ cb,
                                                const float* __restrict__ g,
                                                const float* __restrict__ bt,
                                                ushort* __restrict__ x1b) {
  int tid = threadIdx.x;
  int tok = blockIdx.x * 4 + (tid >> 6);
  int lane = tid & 63;
  size_t base = (size_t)tok * 256 + lane * 4;
  float4 c = *(const float4*)(cb + lane * 4);
  float4 v = c;
#pragma unroll
  for (int z = 0; z < 4; ++z) {
    float4 p = *(const float4*)(part + base + (size_t)z * 524288);
    v.x += p.x; v.y += p.y; v.z += p.z; v.w += p.w;
  }
  float s1 = v.x + v.y + v.z + v.w;
  float s2 = v.x * v.x + v.y * v.y + v.z * v.z + v.w * v.w;
#pragma unroll
  for (int o = 1; o < 64; o <<= 1) {
    s1 += __shfl_xor(s1, o, 64);
    s2 += __shfl_xor(s2, o, 64);
  }
  float mu = s1 * (1.f / 256.f);
  float var = s2 * (1.f / 256.f) - mu * mu;
  float rstd = rsqrtf(var + LN_EPS);
  float4 gg = *(const float4*)(g + lane * 4);
  float4 bb = *(const float4*)(bt + lane * 4);
  ushort4 o4 = {f2bf((v.x - mu) * rstd * gg.x + bb.x),
                f2bf((v.y - mu) * rstd * gg.y + bb.y),
                f2bf((v.z - mu) * rstd * gg.z + bb.z),
                f2bf((v.w - mu) * rstd * gg.w + bb.w)};
  *(ushort4*)(x1b + base) = o4;
}

// ---------------------------------------------------------------------------
// KV projection GEMM, K-step 64 via twin 32-col tiles. (r10 passing verbatim.)
// Grid (16 m, 8 n): same-A blocks differ by 16 in linear id -> same XCD.
// ---------------------------------------------------------------------------
__global__ __launch_bounds__(256) void kv_gemm(const ushort* __restrict__ A,
                                               const ushort* __restrict__ Bw,
                                               const float* __restrict__ bias,
                                               ushort* __restrict__ aux,
                                               ushort* __restrict__ aux2) {
  __shared__ __attribute__((aligned(16))) ushort As[2][128 * 32];
  __shared__ __attribute__((aligned(16))) ushort Bs[2][64 * 32];
  int tid = threadIdx.x;
  int lane = tid & 63, w = tid >> 6;
  int m0 = blockIdx.x * 128, n0 = blockIdx.y * 64;
  int arow0 = w * 16 + (lane >> 2);
  int acol = (lane & 3) * 8;
  f32x4 acc[2][4];
#pragma unroll
  for (int i = 0; i < 2; ++i)
#pragma unroll
    for (int j = 0; j < 4; ++j) acc[i][j] = (f32x4){0.f, 0.f, 0.f, 0.f};

  for (int k0 = 0; k0 < 256; k0 += 64) {
    __syncthreads();
#pragma unroll
    for (int s = 0; s < 2; ++s) {
#pragma unroll
      for (int t = 0; t < 2; ++t) {
        int row = arow0 + t * 64;
        gload_lds16(A + ((size_t)(m0 + row) * 256 + k0 + s * 32 + acol),
                    &As[s][t * 2048 + w * 512]);
      }
      gload_lds16(Bw + ((size_t)(n0 + w * 16 + (lane >> 2)) * 256 + k0 + s * 32 + acol),
                  &Bs[s][w * 512]);
    }
    __syncthreads();
    int qk = (lane >> 4) * 8, l15 = lane & 15;
#pragma unroll
    for (int s = 0; s < 2; ++s) {
      bf16x8 a0 = *(const bf16x8*)&As[s][(w * 32 + l15) * 32 + qk];
      bf16x8 a1 = *(const bf16x8*)&As[s][(w * 32 + 16 + l15) * 32 + qk];
#pragma unroll
      for (int j = 0; j < 4; ++j) {
        bf16x8 bj = *(const bf16x8*)&Bs[s][(j * 16 + l15) * 32 + qk];
        acc[0][j] = __builtin_amdgcn_mfma_f32_16x16x32_bf16(a0, bj, acc[0][j], 0, 0, 0);
        acc[1][j] = __builtin_amdgcn_mfma_f32_16x16x32_bf16(a1, bj, acc[1][j], 0, 0, 0);
      }
    }
  }
  int l15 = lane & 15, q = lane >> 4;
#pragma unroll
  for (int i = 0; i < 2; ++i) {
    int rowb = m0 + w * 32 + i * 16 + q * 4;
    int b = rowb >> 8, mloc = rowb & 255;
#pragma unroll
    for (int j = 0; j < 4; ++j) {
      int col = n0 + j * 16 + l15;
      float bv = bias[col];
      if (col < 256) {  // K half
#pragma unroll
        for (int r = 0; r < 4; ++r)
          aux[(size_t)(b * 256 + mloc + r) * 256 + col] = f2bf(acc[i][j][r] + bv);
      } else {  // V half -> vT[((b*8+h)*32+d)][m]
        int c2 = col - 256, h = c2 >> 5, d = c2 & 31;
        unsigned lo = (unsigned)f2bf(acc[i][j][0] + bv) |
                      ((unsigned)f2bf(acc[i][j][1] + bv) << 16);
        unsigned hi = (unsigned)f2bf(acc[i][j][2] + bv) |
                      ((unsigned)f2bf(acc[i][j][3] + bv) << 16);
        *(uint2*)(aux2 + ((size_t)((b * 8 + h) * 32 + d) * 256 + mloc)) =
            make_uint2(lo, hi);
      }
    }
  }
}

// ---------------------------------------------------------------------------
// MFMA flash attention v8 (r10 passing version, verbatim): 2-deep software
// pipeline over t; double per-wave P buffer; compile-time buffer selection;
// rule-#18 fence between pack(t) writes and PV(t) reads.
// ---------------------------------------------------------------------------
__global__ __launch_bounds__(256) void attn_mfma(const ushort* __restrict__ qbb,
                                                 const ushort* __restrict__ kb,
                                                 const ushort* __restrict__ vT,
                                                 ushort* __restrict__ aob) {
  // 67584 B: first 32 KB doubles as K/V staging, then 4 waves x 2 P buffers.
  __shared__ __attribute__((aligned(16))) ushort sh[2 * 4 * 16 * 264];
  int bid = blockIdx.x;  // 512: b = bid&7 (XCD-local), h = (bid>>3)&7, cp = bid>>6
  int b = bid & 7, h = (bid >> 3) & 7, cp = bid >> 6;
  int tid = threadIdx.x, lane = tid & 63, w = tid >> 6;
  int l15 = lane & 15, quad = lane >> 4;

  // ---- stage K-head -> sh[0..8192) as [m][32]; V-head -> sh[8192..16384) as [d][256]
  {
    const ushort* srcK = kb + (size_t)(b * 256 + w * 64 + (lane >> 2)) * 256 +
                         h * 32 + (lane & 3) * 8;
#pragma unroll
    for (int i = 0; i < 4; ++i)
      gload_lds16(srcK + (size_t)i * 16 * 256, &sh[(w * 64 + i * 16) * 32]);
    const ushort* srcV = vT + (size_t)((b * 8 + h) * 32 + w * 8 + (lane >> 5)) * 256 +
                         (lane & 31) * 8;
#pragma unroll
    for (int i = 0; i < 4; ++i)
      gload_lds16(srcV + (size_t)i * 2 * 256, &sh[8192 + (w * 8 + i * 2) * 256]);
  }
  __syncthreads();  // staging visible (drains vmcnt)
  // ---- extract register fragments (one-time)
  bf16x8 kf[16];
#pragma unroll
  for (int mt = 0; mt < 16; ++mt)
    kf[mt] = *(const bf16x8*)&sh[(mt * 16 + l15) * 32 + quad * 8];
  bf16x8 vf[2][8];
#pragma unroll
  for (int j = 0; j < 2; ++j)
#pragma unroll
    for (int kc = 0; kc < 8; ++kc)
      vf[j][kc] = *(const bf16x8*)&sh[8192 + (j * 16 + l15) * 256 + kc * 32 + quad * 8];
  __syncthreads();  // all frags extracted; sh now reusable as P buffers
  ushort* Pw0 = &sh[w * 2 * 4224];  // wave's buffer 0 (16 x 264)
  ushort* Pw1 = Pw0 + 4224;         // wave's buffer 1

  int q0base = b * 4096 + cp * 512 + w * 64;

  // QK^T + exp + pack for q-tile t into buffer Pw; returns fully-reduced lsum.
  auto QKEP = [&](bf16x8 qf, ushort* Pw) -> float {
    float lsum = 0.f;
#pragma unroll
    for (int mt = 0; mt < 16; ++mt) {
      f32x4 st = __builtin_amdgcn_mfma_f32_16x16x32_bf16(
          kf[mt], qf, (f32x4){0.f, 0.f, 0.f, 0.f}, 0, 0, 0);
      float e0 = __builtin_amdgcn_exp2f(st[0]);
      float e1 = __builtin_amdgcn_exp2f(st[1]);
      float e2 = __builtin_amdgcn_exp2f(st[2]);
      float e3 = __builtin_amdgcn_exp2f(st[3]);
      lsum += e0 + e1 + e2 + e3;  // pre-round sum; RNE of stored P is mean-zero
      unsigned lo = cvt_pk_bf16(e0, e1);
      unsigned hi = cvt_pk_bf16(e2, e3);
      *(uint2*)(Pw + l15 * 264 + mt * 16 + quad * 4) = make_uint2(lo, hi);
    }
    lsum += __shfl_xor(lsum, 16, 64);
    lsum += __shfl_xor(lsum, 32, 64);
    return lsum;
  };
  auto qptr = [&](int t) {
    int q0 = q0base + ((t & 4) << 6) + (t & 3) * 16;
    return (const bf16x8*)(qbb + (size_t)(q0 + l15) * 256 + h * 32 + quad * 8);
  };

  // prologue: fill buffer 0 for t=0
  float lsum_cur = QKEP(*qptr(0), Pw0);

#pragma unroll
  for (int t = 0; t < 8; ++t) {
    ushort* Prd = (t & 1) ? Pw1 : Pw0;  // compile-time after unroll
    ushort* Pwr = (t & 1) ? Pw0 : Pw1;
    bf16x8 qf_next;
    if (t < 7) qf_next = *qptr(t + 1);  // issue early; hides under fence+PV
    fence_lgkm0();  // pack(t) writes complete & ordered before PV reads
    f32x4 oacc[2] = {{0.f, 0.f, 0.f, 0.f}, {0.f, 0.f, 0.f, 0.f}};
#pragma unroll
    for (int kc = 0; kc < 8; ++kc) {
      bf16x8 pf = *(const bf16x8*)(Prd + l15 * 264 + kc * 32 + quad * 8);
      oacc[0] = __builtin_amdgcn_mfma_f32_16x16x32_bf16(pf, vf[0][kc], oacc[0], 0, 0, 0);
      oacc[1] = __builtin_amdgcn_mfma_f32_16x16x32_bf16(pf, vf[1][kc], oacc[1], 0, 0, 0);
    }
    // QK+exp+pack for t+1 (independent of PV above -> scheduler interleaves)
    float lsum_next = 0.f;
    if (t < 7) lsum_next = QKEP(qf_next, Pwr);
    // epilogue for t
    float linv[4];
#pragma unroll
    for (int r = 0; r < 4; ++r)
      linv[r] = __builtin_amdgcn_rcpf(__shfl(lsum_cur, quad * 4 + r, 64));
    int q0 = q0base + ((t & 4) << 6) + (t & 3) * 16;
    ushort* ob = aob + (size_t)q0 * 256 + h * 32;
#pragma unroll
    for (int j = 0; j < 2; ++j)
#pragma unroll
      for (int r = 0; r < 4; ++r) {
        unsigned uo = __float_as_uint(oacc[j][r] * linv[r]) + 0x8000u;
        ob[(size_t)(quad * 4 + r) * 256 + j * 16 + l15] = (ushort)(uo >> 16);
      }
    lsum_cur = lsum_next;
  }
}

// ---------------------------------------------------------------------------
extern "C" void kernel_launch(void* const* d_in, const int* in_sizes, int n_in,
                              void* d_out, int out_size, void* d_ws, size_t ws_size,
                              hipStream_t stream) {
  const float* x = (const float*)d_in[0];
  const float* conv_w = (const float*)d_in[1];
  const float* conv_b = (const float*)d_in[2];
  const float* ln_g = (const float*)d_in[3];
  const float* ln_b = (const float*)d_in[4];
  const float* kv_w = (const float*)d_in[5];
  const float* kv_b = (const float*)d_in[6];
  const float* q_w = (const float*)d_in[7];
  const float* q_b = (const float*)d_in[8];
  const float* out_w = (const float*)d_in[9];
  const float* out_b = (const float*)d_in[10];

  // workspace (~22.4 MB)
  ushort* xb = (ushort*)d_ws;                  // 8,388,608 bf16; aliased as aob later
  ushort* wTb = xb + 8388608;                  // 1,048,576 bf16
  ushort* qwb = wTb + 1048576;                 // 65,536
  ushort* kvwb = qwb + 65536;                  // 131,072
  ushort* owb = kvwb + 131072;                 // 65,536
  ushort* x1b = owb + 65536;                   // 524,288 bf16
  ushort* kb = x1b + 524288;                   // 524,288 bf16: K [b*256+m][256]
  ushort* vT = kb + 524288;                    // 524,288 bf16: V^T [((b*8+h)*32+d)][m]
  ushort* aob = xb;                            // attention out, reuses xb
  // d_out (33.55 MB fp32) doubles as scratch before the final projection:
  float* part = (float*)d_out;                 // 4 x 524,288 f32 conv partials
  ushort* qbb = (ushort*)((float*)d_out + 4194304);  // 8,388,608 bf16 Q

  prep_kernel<<<2560, 256, 0, stream>>>(x, xb, q_w, kv_w, out_w, conv_w,
                                        qwb, kvwb, owb, wTb);
  // merged: conv patch-GEMM split-K=4 (blocks 0-255) + Q projection (256-767)
  convq_kernel<<<768, 256, 0, stream>>>(xb, wTb, part, qwb, q_b, qbb);
  // fused reduce(4) + bias + LayerNorm -> x1b bf16 (wave-per-token)
  ln_fused<<<512, 256, 0, stream>>>(part, conv_b, ln_g, ln_b, x1b);
  // KV projection -> K bf16 (kb) + V^T bf16 (vT)
  kv_gemm<<<dim3(16, 8), 256, 0, stream>>>(x1b, kvwb, kv_b, kb, vT);
  // MFMA flash attention -> aob bf16 (aliases xb; xb dead after convq)
  attn_mfma<<<512, 256, 0, stream>>>(qbb, kb, vT, aob);
  // output projection -> d_out fp32 (overwrites the scratch halves)
  breg_gemm_f32<<<dim3(128, 4), 256, 0, stream>>>(aob, owb, out_b, (float*)d_out);
}